// Round 14
// baseline (35.404 us; speedup 1.0000x reference)
//
#include <hip/hip_runtime.h>
#include <math.h>

#define NQ 7
#define DIM 128
#define NLAYERS 3
#define ROWS 64
#define LDS_S 136   // LDS row stride in bf16 units: 272 B = 17*16B (aligned b128, 2-way banks)

typedef __attribute__((ext_vector_type(8))) short bf16x8;
typedef __attribute__((ext_vector_type(4))) float f32x4;
typedef __attribute__((ext_vector_type(2))) float f32x2;
typedef __attribute__((ext_vector_type(4))) unsigned short us4;

__device__ __forceinline__ unsigned short f2bf(float x) {
    union { float f; unsigned int u; } v; v.f = x;
    unsigned int r = v.u + 0x7fff + ((v.u >> 16) & 1);   // RNE
    return (unsigned short)(r >> 16);
}
__device__ __forceinline__ f32x2 sp(float x) { return (f32x2){x, x}; }
__device__ __forceinline__ f32x2 sel2(int c, f32x2 a, f32x2 b) {
    f32x2 r; r.x = c ? a.x : b.x; r.y = c ? a.y : b.y; return r;
}

// ===========================================================================
// Compile-time GF(2) linear algebra for CNOT-permutation deferral.
// ===========================================================================
constexpr int cperm(int k, int c, int t) {
    return k ^ (((k >> (6 - c)) & 1) << (6 - t));
}
constexpr int lgather(int k, int s) {
    int r = k;
    for (int i = 6; i >= 0; --i) r = cperm(r, i, (i + s) % 7);
    return r;
}

struct Mat { int c[7]; };   // c[j] = image of e_j (7-bit)

constexpr Mat ID{{1, 2, 4, 8, 16, 32, 64}};

constexpr int parity7(int x) { x ^= x >> 4; x ^= x >> 2; x ^= x >> 1; return x & 1; }

constexpr int mapv(const Mat& A, int v) {
    int r = 0;
    for (int j = 0; j < 7; ++j) if ((v >> j) & 1) r ^= A.c[j];
    return r;
}
constexpr Mat matmul(const Mat& A, const Mat& B) {   // A∘B
    Mat m{};
    for (int j = 0; j < 7; ++j) m.c[j] = mapv(A, B.c[j]);
    return m;
}
constexpr Mat matG(int L) {   // CNOT-block gather map g for layer L
    Mat m{};
    for (int j = 0; j < 7; ++j) m.c[j] = lgather(1 << j, L + 1);
    return m;
}
constexpr Mat matinv(const Mat& A) {
    int M[7] = {};
    for (int r = 0; r < 7; ++r) {
        int row = 0;
        for (int j = 0; j < 7; ++j) row |= ((A.c[j] >> r) & 1) << j;
        M[r] = row | (1 << (7 + r));
    }
    for (int col = 0; col < 7; ++col) {
        int piv = col;
        while (!((M[piv] >> col) & 1)) ++piv;
        int t = M[col]; M[col] = M[piv]; M[piv] = t;
        for (int r = 0; r < 7; ++r)
            if (r != col && ((M[r] >> col) & 1)) M[r] ^= M[col];
    }
    Mat inv{};
    for (int j = 0; j < 7; ++j) {
        int c = 0;
        for (int r = 0; r < 7; ++r) c |= ((M[r] >> (7 + j)) & 1) << r;
        inv.c[j] = c;
    }
    return inv;
}
constexpr bool isident(const Mat& A) {
    for (int j = 0; j < 7; ++j) if (A.c[j] != (1 << j)) return false;
    return true;
}

// λ after each CNOT block: λ' = g^{-1} ∘ λ
constexpr Mat LAM1  = matinv(matG(0));
constexpr Mat LAM2  = matmul(matinv(matG(1)), LAM1);
constexpr Mat LAM3  = matmul(matinv(matG(2)), LAM2);
constexpr Mat LAM1I = matG(0);
constexpr Mat LAM2I = matinv(LAM2);
static_assert(isident(matmul(LAM1, LAM1I)), "lam1 inv");
static_assert(isident(matmul(LAM2, LAM2I)), "lam2 inv");
static_assert(isident(matmul(matG(2), matmul(LAM3, matinv(LAM2)))), "lam3 chain");

// row b of λ as a bitmask over physical bits: <row,p> = bit b of λ(p)
constexpr int rowmask(const Mat& A, int b) {
    int r = 0;
    for (int j = 0; j < 7; ++j) r |= ((A.c[j] >> b) & 1) << j;
    return r;
}
// physical Walsh mask for logical mask m: M = λᵀ m
constexpr int featM(const Mat& A, int m) {
    int M = 0;
    for (int j = 0; j < 7; ++j) M |= parity7(A.c[j] & m) << j;
    return M;
}
constexpr int szzmask(int i) { return (1 << (6 - i)) | (1 << (6 - ((i + 1) % 7))); }
constexpr int kmask(int k) { return (k < 7) ? (64 >> k) : szzmask(k - 7); }
// packed feature table: 4 entries of 8 bits each (entry = featM(LAM3, kmask))
constexpr unsigned pack_feat(int base) {
    unsigned r = 0;
    for (int j = 0; j < 4; ++j) {
        int k = base + j;
        unsigned e = (k < 14) ? (unsigned)featM(LAM3, kmask(k)) : 0u;
        r |= e << (8 * j);
    }
    return r;
}

// ===========================================================================
// Cross-lane xor-exchange: DPP for {1,2,3,7,8,15}, ds_swizzle for <32, else shfl.
// ===========================================================================
template<int M>
__device__ __forceinline__ float xsh(float v) {
    if constexpr (M == 1 || M == 2 || M == 3) {
        constexpr int ctrl = (0 ^ M) | ((1 ^ M) << 2) | ((2 ^ M) << 4) | ((3 ^ M) << 6);
        return __int_as_float(__builtin_amdgcn_update_dpp(
            __float_as_int(v), __float_as_int(v), ctrl, 0xF, 0xF, true));
    } else if constexpr (M == 7) {
        return __int_as_float(__builtin_amdgcn_update_dpp(
            __float_as_int(v), __float_as_int(v), 0x141, 0xF, 0xF, true));
    } else if constexpr (M == 8) {
        return __int_as_float(__builtin_amdgcn_update_dpp(   // row_ror:8 == xor 8
            __float_as_int(v), __float_as_int(v), 0x128, 0xF, 0xF, true));
    } else if constexpr (M == 15) {
        return __int_as_float(__builtin_amdgcn_update_dpp(
            __float_as_int(v), __float_as_int(v), 0x140, 0xF, 0xF, true));
    } else if constexpr (M < 32) {
        return __int_as_float(__builtin_amdgcn_ds_swizzle(   // xor within 32
            __float_as_int(v), (M << 10) | 0x1F));
    } else {
        return __shfl_xor(v, M, 64);
    }
}
template<int M>
__device__ __forceinline__ f32x2 xsh2(f32x2 v) {
    f32x2 r; r.x = xsh<M>(v.x); r.y = xsh<M>(v.y); return r;
}

__device__ __forceinline__ float bpermf(int addr, float v) {
    return __int_as_float(__builtin_amdgcn_ds_bpermute(addr, __float_as_int(v)));
}

// ===========================================================================
// Deferred-permutation RY gate (one f32x2 chain = 2 batch elements).
// ===========================================================================
template<int D, int R>
__device__ __forceinline__ void ryg(f32x2 c, f32x2 s, int lane,
                                    f32x2& x0r, f32x2& x0i, f32x2& x1r, f32x2& x1i)
{
    constexpr int  DL = D & 63;
    constexpr int  RL = R & 63;
    constexpr bool D6 = (D >> 6) & 1;
    constexpr bool R6 = (R >> 6) & 1;
    int par = __popc(lane & RL) & 1;
    f32x2 ns  = -s;
    f32x2 sg0 = sel2(par, s, ns);
    f32x2 sg1 = R6 ? sel2(par, ns, s) : sg0;
    f32x2 p0r, p0i, p1r, p1i;
    if constexpr (D6) {
        if constexpr (DL == 0) { p0r = x1r; p0i = x1i; p1r = x0r; p1i = x0i; }
        else {
            p0r = xsh2<DL>(x1r); p0i = xsh2<DL>(x1i);
            p1r = xsh2<DL>(x0r); p1i = xsh2<DL>(x0i);
        }
    } else {
        p0r = xsh2<DL>(x0r); p0i = xsh2<DL>(x0i);
        p1r = xsh2<DL>(x1r); p1i = xsh2<DL>(x1i);
    }
    x0r = c * x0r + sg0 * p0r;  x0i = c * x0i + sg0 * p0i;
    x1r = c * x1r + sg1 * p1r;  x1i = c * x1i + sg1 * p1i;
}

// combined data+weight RY gates of layer LYR (1 or 2), TWO chains (4 elems)
template<int LYR, int I>
__device__ __forceinline__ void rygates(
    const float* trig, const f32x2 (&dc)[2][NQ], const f32x2 (&dsn)[2][NQ], int lane,
    f32x2 (&A0r)[2], f32x2 (&A0i)[2], f32x2 (&A1r)[2], f32x2 (&A1i)[2])
{
    if constexpr (I < NQ) {
        constexpr Mat LM  = (LYR == 1) ? LAM1 : LAM2;
        constexpr Mat LMI = (LYR == 1) ? LAM1I : LAM2I;
        constexpr int b   = 6 - I;
        constexpr int D   = mapv(LMI, 1 << b);
        constexpr int R   = rowmask(LM, b);
        float cw = trig[(LYR * NQ + I) * 2 + 0];
        float sw = trig[(LYR * NQ + I) * 2 + 1];
#pragma unroll
        for (int ch = 0; ch < 2; ++ch) {
            f32x2 c = dc[ch][I] * sp(cw) - dsn[ch][I] * sp(sw);   // RY(a)RY(b)=RY(a+b)
            f32x2 s = dsn[ch][I] * sp(cw) + dc[ch][I] * sp(sw);
            ryg<D, R>(c, s, lane, A0r[ch], A0i[ch], A1r[ch], A1i[ch]);
        }
        rygates<LYR, I + 1>(trig, dc, dsn, lane, A0r, A0i, A1r, A1i);
    }
}

// data-independent merged-RZ phase for layer L at physical index p
template<int L, int Q>
__device__ __forceinline__ float rzph(const float* __restrict__ wrz, int p, float th)
{
    if constexpr (Q < NQ) {
        constexpr Mat LM = (L == 0) ? ID : ((L == 1) ? LAM1 : LAM2);
        constexpr int R  = rowmask(LM, 6 - Q);
        float h = 0.5f * wrz[L * NQ + Q];
        th += (__popc(R & p) & 1) ? -h : h;
        return rzph<L, Q + 1>(wrz, p, th);
    } else {
        return th;
    }
}

// table-driven merged RZ (4 LDS loads shared across both chains)
template<int LYR>
__device__ __forceinline__ void rztab(const float* sphz, int lane,
    f32x2 (&A0r)[2], f32x2 (&A0i)[2], f32x2 (&A1r)[2], f32x2 (&A1i)[2])
{
    float c0 = sphz[(LYR * 128 + lane) * 2 + 0];
    float s0 = sphz[(LYR * 128 + lane) * 2 + 1];
    float c1 = sphz[(LYR * 128 + 64 + lane) * 2 + 0];
    float s1 = sphz[(LYR * 128 + 64 + lane) * 2 + 1];
#pragma unroll
    for (int ch = 0; ch < 2; ++ch) {
        f32x2 r, im;
        r = A0r[ch]; im = A0i[ch];
        A0r[ch] = sp(c0) * r  + sp(s0) * im;      // * exp(-i*th)
        A0i[ch] = sp(c0) * im - sp(s0) * r;
        r = A1r[ch]; im = A1i[ch];
        A1r[ch] = sp(c1) * r  + sp(s1) * im;
        A1i[ch] = sp(c1) * im - sp(s1) * r;
    }
}

// Walsh-Hadamard butterfly stage over lane-bit mask M (both chains)
template<int M>
__device__ __forceinline__ void bfly2(int lane, f32x2 (&tp)[2], f32x2 (&tm)[2]) {
    int hi = lane & M;
#pragma unroll
    for (int ch = 0; ch < 2; ++ch) {
        f32x2 pp = xsh2<M>(tp[ch]), pm = xsh2<M>(tm[ch]);
        tp[ch] = sel2(hi, pp - tp[ch], tp[ch] + pp);
        tm[ch] = sel2(hi, pm - tm[ch], tm[ch] + pm);
    }
}

// ---------------------------------------------------------------------------
// Quantum circuit: one wave = FOUR batch elements (two independent f32x2
// chains -> 2x gate-chain ILP at the same VGPR occupancy bin).
//  - weight transposition spread over all 2048 blocks (17 elem/block),
//    loads in prologue, stores in epilogue.
//  - merged-RZ phases precomputed per block into LDS.
//  - feature store: one fully-coalesced 64-lane store (4 elems x 16 slots).
// ---------------------------------------------------------------------------
__global__ __launch_bounds__(256) void circuit_kernel(
    const float* __restrict__ x_q, const float* __restrict__ scales,
    const float* __restrict__ biases,
    const float* __restrict__ wry, const float* __restrict__ wrz,
    const float* __restrict__ ew1, const float* __restrict__ ew2,
    const float* __restrict__ w1,  const float* __restrict__ w2,
    const float* __restrict__ w3,  const float* __restrict__ w4,
    float* __restrict__ q_out,
    unsigned short* __restrict__ ew1t, unsigned short* __restrict__ ew2t,
    unsigned short* __restrict__ w1t,  unsigned short* __restrict__ w2t,
    unsigned short* __restrict__ w3t,  unsigned short* __restrict__ w4t,
    int B)
{
    __shared__ float strig[NLAYERS * NQ * 2];
    __shared__ float sphz[NLAYERS * 128 * 2];
    const int tid  = threadIdx.x;
    const int lane = tid & 63;

    // ---- scattered weight-transpose: 17 elements per block, loads issued NOW
    float trv = 0.0f;
    unsigned short* trdst = nullptr;
    {
        int e = blockIdx.x * 17 + tid;
        if (tid < 17 && e < 33280) {
            const float* srcp = nullptr;
            if (e < 16384) {                       // w1t (permuted K)
                int n = e >> 7, kp = e & 127;
                trdst = &w1t[e];
                if (kp < 64)       srcp = &w1[(46 + kp) * 128 + n];
                else if (kp < 78)  srcp = &w1[(kp - 64) * 128 + n];
                else if (kp < 110) srcp = &w1[(kp - 78 + 14) * 128 + n];
            } else if (e < 24576) {                // w2t
                int r = e - 16384, n = r >> 7, k = r & 127;
                trdst = &w2t[r]; srcp = &w2[k * 64 + n];
            } else if (e < 28672) {                // ew1t
                int r = e - 24576, n = r >> 6, k = r & 63;
                trdst = &ew1t[r]; srcp = &ew1[k * 64 + n];
            } else if (e < 30720) {                // ew2t
                int r = e - 28672, n = r >> 6, k = r & 63;
                trdst = &ew2t[r]; srcp = &ew2[k * 32 + n];
            } else if (e < 32768) {                // w3t
                int r = e - 30720, n = r >> 6, k = r & 63;
                trdst = &w3t[r]; srcp = &w3[k * 32 + n];
            } else {                               // w4t (row 0 = w4, rest 0)
                int r = e - 32768, n = r >> 5, k = r & 31;
                trdst = &w4t[r]; srcp = (n == 0) ? &w4[k] : nullptr;
            }
            if (srcp) trv = *srcp;
        }
    }

    // ---- weight-RY trig table (batch-uniform)
    if (tid < NLAYERS * NQ) {
        float hy = 0.5f * wry[tid];
        strig[tid * 2 + 0] = __cosf(hy);
        strig[tid * 2 + 1] = __sinf(hy);
    }
    // ---- merged-RZ phase table: 384 entries (layer, physical index p)
    for (int e2 = tid; e2 < NLAYERS * 128; e2 += 256) {
        int l = e2 >> 7, p = e2 & 127;
        float th = (l == 0) ? rzph<0, 0>(wrz, p, 0.0f)
                 : (l == 1) ? rzph<1, 0>(wrz, p, 0.0f)
                            : rzph<2, 0>(wrz, p, 0.0f);
        sphz[e2 * 2 + 0] = __cosf(th);
        sphz[e2 * 2 + 1] = __sinf(th);
    }
    __syncthreads();

    int gtid = blockIdx.x * blockDim.x + tid;
    int wv   = gtid >> 6;
    int e0   = wv * 4;
    if (e0 >= B) {
        if (trdst) *trdst = f2bf(trv);
        return;
    }

    // data half-angle trig (hw sin/cos), 4 elements in 2 f32x2 chains
    f32x2 dc[2][NQ], dsn[2][NQ];
#pragma unroll
    for (int ch = 0; ch < 2; ++ch)
#pragma unroll
        for (int i = 0; i < NQ; ++i) {
            int eb = e0 + 2 * ch;
            float h0 = 0.5f * fmaf(scales[i], x_q[(size_t)eb * NQ + i], biases[i]);
            float h1 = 0.5f * fmaf(scales[i], x_q[(size_t)(eb + 1) * NQ + i], biases[i]);
            dc[ch][i]  = (f32x2){__cosf(h0), __cosf(h1)};
            dsn[ch][i] = (f32x2){__sinf(h0), __sinf(h1)};
        }

    // layer-0 combined (data+weight) RY block on |0...0>: product state (λ=id)
    f32x2 A0r[2], A0i[2], A1r[2], A1i[2];
#pragma unroll
    for (int ch = 0; ch < 2; ++ch) {
        f32x2 cl[NQ], sl[NQ];
#pragma unroll
        for (int i = 0; i < NQ; ++i) {
            float cw = strig[i * 2 + 0], sw = strig[i * 2 + 1];
            cl[i] = dc[ch][i] * sp(cw) - dsn[ch][i] * sp(sw);
            sl[i] = dsn[ch][i] * sp(cw) + dc[ch][i] * sp(sw);
        }
        f32x2 f1 = sel2(lane & 32, sl[1], cl[1]);
        f32x2 f2 = sel2(lane & 16, sl[2], cl[2]);
        f32x2 f3 = sel2(lane &  8, sl[3], cl[3]);
        f32x2 f4 = sel2(lane &  4, sl[4], cl[4]);
        f32x2 f5 = sel2(lane &  2, sl[5], cl[5]);
        f32x2 f6 = sel2(lane &  1, sl[6], cl[6]);
        f32x2 pr = (f1 * f2) * (f3 * f4) * (f5 * f6);
        A0r[ch] = pr * cl[0]; A0i[ch] = sp(0.0f);
        A1r[ch] = pr * sl[0]; A1i[ch] = sp(0.0f);
    }

    rztab<0>(sphz, lane, A0r, A0i, A1r, A1i);
    // CNOT block 1 deferred (λ -> LAM1)
    rygates<1, 0>(strig, dc, dsn, lane, A0r, A0i, A1r, A1i);
    rztab<1>(sphz, lane, A0r, A0i, A1r, A1i);
    // CNOT block 2 deferred (λ -> LAM2)
    rygates<2, 0>(strig, dc, dsn, lane, A0r, A0i, A1r, A1i);
    rztab<2>(sphz, lane, A0r, A0i, A1r, A1i);
    // CNOT block 3 deferred (λ -> LAM3, folded into feature masks)

    f32x2 tp[2], tm[2];
#pragma unroll
    for (int ch = 0; ch < 2; ++ch) {
        f32x2 p0 = A0r[ch] * A0r[ch] + A0i[ch] * A0i[ch];
        f32x2 p1 = A1r[ch] * A1r[ch] + A1i[ch] * A1i[ch];
        tp[ch] = p0 + p1;   // physical-Walsh masks with bit6 = 0
        tm[ch] = p0 - p1;   // physical-Walsh masks with bit6 = 1
    }

    bfly2<1>(lane, tp, tm);
    bfly2<2>(lane, tp, tm);
    bfly2<4>(lane, tp, tm);
    bfly2<8>(lane, tp, tm);
    bfly2<16>(lane, tp, tm);
    bfly2<32>(lane, tp, tm);

    // ---- fully-coalesced feature store: lane L writes q_out[e0*16 + L]
    //      slot k = L&15 of element e = L>>4 (pads 14,15 junk, mlp overwrites)
    {
        constexpr unsigned P0 = pack_feat(0),  P1 = pack_feat(4);
        constexpr unsigned P2 = pack_feat(8),  P3 = pack_feat(12);
        int k = lane & 15;
        unsigned wlo  = (k & 4) ? P1 : P0;
        unsigned whi  = (k & 4) ? P3 : P2;
        unsigned word = (k & 8) ? whi : wlo;
        unsigned entry = (word >> ((k & 3) * 8)) & 127u;
        int addr   = (int)(entry & 63u) << 2;
        int useTm  = (int)(entry & 64u);
        int e      = lane >> 4;           // element 0..3
        float p0v = bpermf(addr, tp[0].x), p1v = bpermf(addr, tp[0].y);
        float p2v = bpermf(addr, tp[1].x), p3v = bpermf(addr, tp[1].y);
        float m0v = bpermf(addr, tm[0].x), m1v = bpermf(addr, tm[0].y);
        float m2v = bpermf(addr, tm[1].x), m3v = bpermf(addr, tm[1].y);
        float vp = (e & 2) ? ((e & 1) ? p3v : p2v) : ((e & 1) ? p1v : p0v);
        float vm = (e & 2) ? ((e & 1) ? m3v : m2v) : ((e & 1) ? m1v : m0v);
        float val = useTm ? vm : vp;
        q_out[(size_t)e0 * 16 + lane] = val;
    }

    // ---- epilogue: transpose store (load latency hidden by circuit above)
    if (trdst) *trdst = f2bf(trv);
}

// ---------------------------------------------------------------------------
// One MFMA layer (cooperative, 8 waves): Y[64][N] = act(X[64][K]@Wt^T + b).
//   8 waves split NTILES x 4 mtiles: each wave owns ONE ntile (= wv % NTILES)
//   and MT_W = NTILES/2 mtiles starting at (wv / NTILES) * MT_W.
// ---------------------------------------------------------------------------
template<int K, int NTILES, bool RELU>
__device__ __forceinline__ void layer_mfma8(
    const unsigned short* src, unsigned short* dst,
    const unsigned short* __restrict__ wt, const float* __restrict__ bias,
    int dstcol, int lane, int wv)
{
    constexpr int KB   = K / 32;
    constexpr int MT_W = (NTILES * 4) / 8;     // mtiles per wave
    const int ntile  = wv % NTILES;
    const int mtile0 = (wv / NTILES) * MT_W;
    const int lcol = lane & 15;
    const int lrow = lane >> 4;

    bf16x8 bfrag[KB];
    float  bb = bias[ntile * 16 + lcol];
#pragma unroll
    for (int kb = 0; kb < KB; ++kb)
        bfrag[kb] = *(const bf16x8*)&wt[(ntile * 16 + lcol) * K + kb * 32 + lrow * 8];

#pragma unroll
    for (int m = 0; m < MT_W; ++m) {
        const int mt = mtile0 + m;
        bf16x8 afrag[KB];
#pragma unroll
        for (int kb = 0; kb < KB; ++kb)
            afrag[kb] = *(const bf16x8*)&src[(mt * 16 + lcol) * LDS_S + kb * 32 + lrow * 8];

        f32x4 acc = (f32x4){bb, bb, bb, bb};
#pragma unroll
        for (int kb = 0; kb < KB; ++kb)
            acc = __builtin_amdgcn_mfma_f32_16x16x32_bf16(afrag[kb], bfrag[kb], acc, 0, 0, 0);

#pragma unroll
        for (int r = 0; r < 4; ++r) {
            float v = acc[r];
            if (RELU) v = fmaxf(v, 0.0f);
            dst[(mt * 16 + lrow * 4 + r) * LDS_S + dstcol + ntile * 16 + lcol] = f2bf(v);
        }
    }
}

// ---------------------------------------------------------------------------
// Fused MFMA MLP (cooperative, ROWS=64, 8 waves/block = 512 threads).
// ---------------------------------------------------------------------------
__global__ __launch_bounds__(512) void mlp_kernel(
    const float* __restrict__ q_out, const float* __restrict__ x_c,
    const unsigned short* __restrict__ ew1t, const float* __restrict__ eb1,
    const unsigned short* __restrict__ ew2t, const float* __restrict__ eb2,
    const unsigned short* __restrict__ w1t,  const float* __restrict__ b1,
    const unsigned short* __restrict__ w2t,  const float* __restrict__ b2,
    const unsigned short* __restrict__ w3t,  const float* __restrict__ b3,
    const unsigned short* __restrict__ w4t,  const float* __restrict__ b4,
    float* __restrict__ out, int B)
{
    __shared__ unsigned short BufA[ROWS * LDS_S];
    __shared__ unsigned short BufB[ROWS * LDS_S];

    const int tid  = threadIdx.x;
    const int lane = tid & 63;
    const int wv   = __builtin_amdgcn_readfirstlane(tid >> 6);   // 0..7
    const int base = blockIdx.x * ROWS;

    // ---- stage x_c (fp32 -> bf16) into BufA cols 0-63
    {
        const float4* xr = (const float4*)(x_c + (size_t)base * 64);
        for (int i = tid; i < 1024; i += 512) {
            int row = i >> 4, fc = i & 15;
            float4 v = xr[i];
            us4 b;
            b.x = f2bf(v.x); b.y = f2bf(v.y); b.z = f2bf(v.z); b.w = f2bf(v.w);
            *(us4*)&BufA[row * LDS_S + fc * 4] = b;
        }
    }
    // ---- stage q_out (stride 16) into BufA cols 64-79; junk cols 78-79 are
    //      overwritten by encL2 before fusion L1 reads them
    for (int i = tid; i < 1024; i += 512) {
        int row = i >> 4, k = i & 15;
        BufA[row * LDS_S + 64 + k] = f2bf(q_out[(size_t)(base + row) * 16 + k]);
    }
    // ---- zero pad cols 110-127
    for (int i = tid; i < 64 * 18; i += 512) {
        int row = i / 18, k = i - row * 18;
        BufA[row * LDS_S + 110 + k] = 0;
    }
    __syncthreads();

    layer_mfma8<64, 4, true>(BufA, BufB, ew1t, eb1, 0, lane, wv);
    __syncthreads();
    layer_mfma8<64, 2, true>(BufB, BufA, ew2t, eb2, 78, lane, wv);
    __syncthreads();
    layer_mfma8<128, 8, true>(BufA, BufB, w1t, b1, 0, lane, wv);
    __syncthreads();
    layer_mfma8<128, 4, true>(BufB, BufA, w2t, b2, 0, lane, wv);
    __syncthreads();
    layer_mfma8<64, 2, true>(BufA, BufB, w3t, b3, 0, lane, wv);
    __syncthreads();

    // ---- fusion L4: out = h3 @ w4 + b4   [K=32, N=1(pad 16)], waves 0-3
    if (wv < 4) {
        const int lcol = lane & 15;
        const int lrow = lane >> 4;
        bf16x8 a = *(const bf16x8*)&BufB[(wv * 16 + lcol) * LDS_S + lrow * 8];
        bf16x8 b = *(const bf16x8*)&w4t[lcol * 32 + lrow * 8];
        float bv = b4[0];
        f32x4 acc = (f32x4){bv, bv, bv, bv};
        acc = __builtin_amdgcn_mfma_f32_16x16x32_bf16(a, b, acc, 0, 0, 0);
        if (lcol == 0) {
            float4 o; o.x = acc[0]; o.y = acc[1]; o.z = acc[2]; o.w = acc[3];
            *(float4*)(out + base + wv * 16 + lrow * 4) = o;
        }
    }
}

// ---------------------------------------------------------------------------
extern "C" void kernel_launch(void* const* d_in, const int* in_sizes, int n_in,
                              void* d_out, int out_size, void* d_ws, size_t ws_size,
                              hipStream_t stream)
{
    const float* x_q     = (const float*)d_in[0];
    const float* x_c     = (const float*)d_in[1];
    const float* scales  = (const float*)d_in[2];
    const float* biases  = (const float*)d_in[3];
    const float* wry     = (const float*)d_in[4];
    const float* wrz     = (const float*)d_in[5];
    const float* enc_w1  = (const float*)d_in[6];
    const float* enc_b1  = (const float*)d_in[7];
    const float* enc_w2  = (const float*)d_in[8];
    const float* enc_b2  = (const float*)d_in[9];
    const float* fus_w1  = (const float*)d_in[10];
    const float* fus_b1  = (const float*)d_in[11];
    const float* fus_w2  = (const float*)d_in[12];
    const float* fus_b2  = (const float*)d_in[13];
    const float* fus_w3  = (const float*)d_in[14];
    const float* fus_b3  = (const float*)d_in[15];
    const float* fus_w4  = (const float*)d_in[16];
    const float* fus_b4  = (const float*)d_in[17];
    float* out = (float*)d_out;

    int B = in_sizes[0] / NQ;   // 32768

    float* ws    = (float*)d_ws;
    float* q_out = ws;                              // B*16 floats (padded)
    unsigned short* wsh = (unsigned short*)(q_out + (size_t)B * 16);
    unsigned short* w1t  = wsh;                     // 16384
    unsigned short* w2t  = w1t + 16384;             // 8192
    unsigned short* ew1t = w2t + 8192;              // 4096
    unsigned short* ew2t = ew1t + 4096;             // 2048
    unsigned short* w3t  = ew2t + 2048;             // 2048
    unsigned short* w4t  = w3t + 2048;              // 512

    int circ_blocks = ((B / 4) * 64 + 255) / 256;   // 4 elements per wave, 2048
    circuit_kernel<<<circ_blocks, 256, 0, stream>>>(
        x_q, scales, biases, wry, wrz,
        enc_w1, enc_w2, fus_w1, fus_w2, fus_w3, fus_w4,
        q_out, ew1t, ew2t, w1t, w2t, w3t, w4t, B);

    int row_blocks = B / ROWS;   // 512
    mlp_kernel<<<row_blocks, 512, 0, stream>>>(q_out, x_c,
                                               ew1t, enc_b1, ew2t, enc_b2,
                                               w1t, fus_b1, w2t, fus_b2,
                                               w3t, fus_b3, w4t, fus_b4,
                                               out, B);
}

// Round 15
// 33.816 us; speedup vs baseline: 1.0470x; 1.0470x over previous
//
#include <hip/hip_runtime.h>
#include <math.h>

#define NQ 7
#define DIM 128
#define NLAYERS 3
#define ROWS 64
#define LDS_S 136   // LDS row stride in bf16 units: 272 B = 17*16B (aligned b128, 2-way banks)

typedef __attribute__((ext_vector_type(8))) short bf16x8;
typedef __attribute__((ext_vector_type(4))) float f32x4;
typedef __attribute__((ext_vector_type(2))) float f32x2;
typedef __attribute__((ext_vector_type(4))) unsigned short us4;

__device__ __forceinline__ unsigned short f2bf(float x) {
    union { float f; unsigned int u; } v; v.f = x;
    unsigned int r = v.u + 0x7fff + ((v.u >> 16) & 1);   // RNE
    return (unsigned short)(r >> 16);
}
__device__ __forceinline__ f32x2 sp(float x) { return (f32x2){x, x}; }
__device__ __forceinline__ f32x2 sel2(int c, f32x2 a, f32x2 b) {
    f32x2 r; r.x = c ? a.x : b.x; r.y = c ? a.y : b.y; return r;
}

// ===========================================================================
// Compile-time GF(2) linear algebra for CNOT-permutation deferral.
// ===========================================================================
constexpr int cperm(int k, int c, int t) {
    return k ^ (((k >> (6 - c)) & 1) << (6 - t));
}
constexpr int lgather(int k, int s) {
    int r = k;
    for (int i = 6; i >= 0; --i) r = cperm(r, i, (i + s) % 7);
    return r;
}

struct Mat { int c[7]; };   // c[j] = image of e_j (7-bit)

constexpr Mat ID{{1, 2, 4, 8, 16, 32, 64}};

constexpr int parity7(int x) { x ^= x >> 4; x ^= x >> 2; x ^= x >> 1; return x & 1; }

constexpr int mapv(const Mat& A, int v) {
    int r = 0;
    for (int j = 0; j < 7; ++j) if ((v >> j) & 1) r ^= A.c[j];
    return r;
}
constexpr Mat matmul(const Mat& A, const Mat& B) {   // A∘B
    Mat m{};
    for (int j = 0; j < 7; ++j) m.c[j] = mapv(A, B.c[j]);
    return m;
}
constexpr Mat matG(int L) {   // CNOT-block gather map g for layer L
    Mat m{};
    for (int j = 0; j < 7; ++j) m.c[j] = lgather(1 << j, L + 1);
    return m;
}
constexpr Mat matinv(const Mat& A) {
    int M[7] = {};
    for (int r = 0; r < 7; ++r) {
        int row = 0;
        for (int j = 0; j < 7; ++j) row |= ((A.c[j] >> r) & 1) << j;
        M[r] = row | (1 << (7 + r));
    }
    for (int col = 0; col < 7; ++col) {
        int piv = col;
        while (!((M[piv] >> col) & 1)) ++piv;
        int t = M[col]; M[col] = M[piv]; M[piv] = t;
        for (int r = 0; r < 7; ++r)
            if (r != col && ((M[r] >> col) & 1)) M[r] ^= M[col];
    }
    Mat inv{};
    for (int j = 0; j < 7; ++j) {
        int c = 0;
        for (int r = 0; r < 7; ++r) c |= ((M[r] >> (7 + j)) & 1) << r;
        inv.c[j] = c;
    }
    return inv;
}
constexpr bool isident(const Mat& A) {
    for (int j = 0; j < 7; ++j) if (A.c[j] != (1 << j)) return false;
    return true;
}

// λ after each CNOT block: λ' = g^{-1} ∘ λ
constexpr Mat LAM1  = matinv(matG(0));
constexpr Mat LAM2  = matmul(matinv(matG(1)), LAM1);
constexpr Mat LAM3  = matmul(matinv(matG(2)), LAM2);
constexpr Mat LAM1I = matG(0);
constexpr Mat LAM2I = matinv(LAM2);
static_assert(isident(matmul(LAM1, LAM1I)), "lam1 inv");
static_assert(isident(matmul(LAM2, LAM2I)), "lam2 inv");
static_assert(isident(matmul(matG(2), matmul(LAM3, matinv(LAM2)))), "lam3 chain");

// row b of λ as a bitmask over physical bits: <row,p> = bit b of λ(p)
constexpr int rowmask(const Mat& A, int b) {
    int r = 0;
    for (int j = 0; j < 7; ++j) r |= ((A.c[j] >> b) & 1) << j;
    return r;
}
// physical Walsh mask for logical mask m: M = λᵀ m
constexpr int featM(const Mat& A, int m) {
    int M = 0;
    for (int j = 0; j < 7; ++j) M |= parity7(A.c[j] & m) << j;
    return M;
}
constexpr int szzmask(int i) { return (1 << (6 - i)) | (1 << (6 - ((i + 1) % 7))); }
constexpr int kmask(int k) { return (k < 7) ? (64 >> k) : szzmask(k - 7); }
// packed feature table: 4 entries of 8 bits each (entry = featM(LAM3, kmask))
constexpr unsigned pack_feat(int base) {
    unsigned r = 0;
    for (int j = 0; j < 4; ++j) {
        int k = base + j;
        unsigned e = (k < 14) ? (unsigned)featM(LAM3, kmask(k)) : 0u;
        r |= e << (8 * j);
    }
    return r;
}

// ===========================================================================
// Cross-lane xor-exchange: DPP for {1,2,3,7,8,15}, ds_swizzle for <32, else shfl.
// ===========================================================================
template<int M>
__device__ __forceinline__ float xsh(float v) {
    if constexpr (M == 1 || M == 2 || M == 3) {
        constexpr int ctrl = (0 ^ M) | ((1 ^ M) << 2) | ((2 ^ M) << 4) | ((3 ^ M) << 6);
        return __int_as_float(__builtin_amdgcn_update_dpp(
            __float_as_int(v), __float_as_int(v), ctrl, 0xF, 0xF, true));
    } else if constexpr (M == 7) {
        return __int_as_float(__builtin_amdgcn_update_dpp(
            __float_as_int(v), __float_as_int(v), 0x141, 0xF, 0xF, true));
    } else if constexpr (M == 8) {
        return __int_as_float(__builtin_amdgcn_update_dpp(   // row_ror:8 == xor 8
            __float_as_int(v), __float_as_int(v), 0x128, 0xF, 0xF, true));
    } else if constexpr (M == 15) {
        return __int_as_float(__builtin_amdgcn_update_dpp(
            __float_as_int(v), __float_as_int(v), 0x140, 0xF, 0xF, true));
    } else if constexpr (M < 32) {
        return __int_as_float(__builtin_amdgcn_ds_swizzle(   // xor within 32
            __float_as_int(v), (M << 10) | 0x1F));
    } else {
        return __shfl_xor(v, M, 64);
    }
}
template<int M>
__device__ __forceinline__ f32x2 xsh2(f32x2 v) {
    f32x2 r; r.x = xsh<M>(v.x); r.y = xsh<M>(v.y); return r;
}

__device__ __forceinline__ float bpermf(int addr, float v) {
    return __int_as_float(__builtin_amdgcn_ds_bpermute(addr, __float_as_int(v)));
}

// ===========================================================================
// Deferred-permutation RY gate (2 elements packed in f32x2).
// ===========================================================================
template<int D, int R>
__device__ __forceinline__ void ryg(f32x2 c, f32x2 s, int lane,
                                    f32x2& x0r, f32x2& x0i, f32x2& x1r, f32x2& x1i)
{
    constexpr int  DL = D & 63;
    constexpr int  RL = R & 63;
    constexpr bool D6 = (D >> 6) & 1;
    constexpr bool R6 = (R >> 6) & 1;
    int par = __popc(lane & RL) & 1;
    f32x2 ns  = -s;
    f32x2 sg0 = sel2(par, s, ns);
    f32x2 sg1 = R6 ? sel2(par, ns, s) : sg0;
    f32x2 p0r, p0i, p1r, p1i;
    if constexpr (D6) {
        if constexpr (DL == 0) { p0r = x1r; p0i = x1i; p1r = x0r; p1i = x0i; }
        else {
            p0r = xsh2<DL>(x1r); p0i = xsh2<DL>(x1i);
            p1r = xsh2<DL>(x0r); p1i = xsh2<DL>(x0i);
        }
    } else {
        p0r = xsh2<DL>(x0r); p0i = xsh2<DL>(x0i);
        p1r = xsh2<DL>(x1r); p1i = xsh2<DL>(x1i);
    }
    x0r = c * x0r + sg0 * p0r;  x0i = c * x0i + sg0 * p0i;
    x1r = c * x1r + sg1 * p1r;  x1i = c * x1i + sg1 * p1i;
}

// combined data+weight RY gates of layer LYR (1 or 2)
template<int LYR, int I>
__device__ __forceinline__ void rygates(
    const float* trig, const f32x2 (&dc)[NQ], const f32x2 (&dsn)[NQ], int lane,
    f32x2& A0r, f32x2& A0i, f32x2& A1r, f32x2& A1i)
{
    if constexpr (I < NQ) {
        constexpr Mat LM  = (LYR == 1) ? LAM1 : LAM2;
        constexpr Mat LMI = (LYR == 1) ? LAM1I : LAM2I;
        constexpr int b   = 6 - I;
        constexpr int D   = mapv(LMI, 1 << b);
        constexpr int R   = rowmask(LM, b);
        float cw = trig[(LYR * NQ + I) * 2 + 0];
        float sw = trig[(LYR * NQ + I) * 2 + 1];
        f32x2 c = dc[I] * sp(cw) - dsn[I] * sp(sw);   // RY(a)RY(b)=RY(a+b)
        f32x2 s = dsn[I] * sp(cw) + dc[I] * sp(sw);
        ryg<D, R>(c, s, lane, A0r, A0i, A1r, A1i);
        rygates<LYR, I + 1>(trig, dc, dsn, lane, A0r, A0i, A1r, A1i);
    }
}

// data-independent merged-RZ phase for layer L at physical index p
// NOTE: layer 2's RZ is mathematically dead (diagonal phase followed only by
// a permutation and |amp|^2) and is never computed.
template<int L, int Q>
__device__ __forceinline__ float rzph(const float* __restrict__ wrz, int p, float th)
{
    if constexpr (Q < NQ) {
        constexpr Mat LM = (L == 0) ? ID : LAM1;
        constexpr int R  = rowmask(LM, 6 - Q);
        float h = 0.5f * wrz[L * NQ + Q];
        th += (__popc(R & p) & 1) ? -h : h;
        return rzph<L, Q + 1>(wrz, p, th);
    } else {
        return th;
    }
}

// table-driven merged RZ: 4 LDS loads + rotation (phases precomputed/block)
template<int LYR>
__device__ __forceinline__ void rztab(const float* sphz, int lane,
    f32x2& A0r, f32x2& A0i, f32x2& A1r, f32x2& A1i)
{
    float c0 = sphz[(LYR * 128 + lane) * 2 + 0];
    float s0 = sphz[(LYR * 128 + lane) * 2 + 1];
    float c1 = sphz[(LYR * 128 + 64 + lane) * 2 + 0];
    float s1 = sphz[(LYR * 128 + 64 + lane) * 2 + 1];
    f32x2 r, im;
    r = A0r; im = A0i;
    A0r = sp(c0) * r  + sp(s0) * im;      // * exp(-i*th)
    A0i = sp(c0) * im - sp(s0) * r;
    r = A1r; im = A1i;
    A1r = sp(c1) * r  + sp(s1) * im;
    A1i = sp(c1) * im - sp(s1) * r;
}

// Walsh-Hadamard butterfly stage over lane-bit mask M
template<int M>
__device__ __forceinline__ void bfly2(int lane, f32x2& tp, f32x2& tm) {
    f32x2 pp = xsh2<M>(tp), pm = xsh2<M>(tm);
    int hi = lane & M;
    tp = sel2(hi, pp - tp, tp + pp);
    tm = sel2(hi, pm - tm, tm + pm);
}

// ---------------------------------------------------------------------------
// Quantum circuit (one wave = 2 batch elements, f32x2-packed).
//  - weight transposition spread over ALL blocks (9 elem/block), loads in
//    prologue, stores in epilogue (latency hidden under circuit compute).
//  - merged-RZ phases (layers 0,1 only — layer 2's RZ is dead) in LDS.
// ---------------------------------------------------------------------------
__global__ __launch_bounds__(256) void circuit_kernel(
    const float* __restrict__ x_q, const float* __restrict__ scales,
    const float* __restrict__ biases,
    const float* __restrict__ wry, const float* __restrict__ wrz,
    const float* __restrict__ ew1, const float* __restrict__ ew2,
    const float* __restrict__ w1,  const float* __restrict__ w2,
    const float* __restrict__ w3,  const float* __restrict__ w4,
    float* __restrict__ q_out,
    unsigned short* __restrict__ ew1t, unsigned short* __restrict__ ew2t,
    unsigned short* __restrict__ w1t,  unsigned short* __restrict__ w2t,
    unsigned short* __restrict__ w3t,  unsigned short* __restrict__ w4t,
    int B)
{
    __shared__ float strig[NLAYERS * NQ * 2];
    __shared__ float sphz[2 * 128 * 2];
    const int tid  = threadIdx.x;
    const int lane = tid & 63;

    // ---- scattered weight-transpose: 9 elements per block, loads issued NOW
    float trv = 0.0f;
    unsigned short* trdst = nullptr;
    {
        int e = blockIdx.x * 9 + tid;
        if (tid < 9 && e < 33280) {
            const float* srcp = nullptr;
            if (e < 16384) {                       // w1t (permuted K)
                int n = e >> 7, kp = e & 127;
                trdst = &w1t[e];
                if (kp < 64)       srcp = &w1[(46 + kp) * 128 + n];
                else if (kp < 78)  srcp = &w1[(kp - 64) * 128 + n];
                else if (kp < 110) srcp = &w1[(kp - 78 + 14) * 128 + n];
            } else if (e < 24576) {                // w2t
                int r = e - 16384, n = r >> 7, k = r & 127;
                trdst = &w2t[r]; srcp = &w2[k * 64 + n];
            } else if (e < 28672) {                // ew1t
                int r = e - 24576, n = r >> 6, k = r & 63;
                trdst = &ew1t[r]; srcp = &ew1[k * 64 + n];
            } else if (e < 30720) {                // ew2t
                int r = e - 28672, n = r >> 6, k = r & 63;
                trdst = &ew2t[r]; srcp = &ew2[k * 32 + n];
            } else if (e < 32768) {                // w3t
                int r = e - 30720, n = r >> 6, k = r & 63;
                trdst = &w3t[r]; srcp = &w3[k * 32 + n];
            } else {                               // w4t (row 0 = w4, rest 0)
                int r = e - 32768, n = r >> 5, k = r & 31;
                trdst = &w4t[r]; srcp = (n == 0) ? &w4[k] : nullptr;
            }
            if (srcp) trv = *srcp;
        }
    }

    // ---- weight-RY trig table (batch-uniform)
    if (tid < NLAYERS * NQ) {
        float hy = 0.5f * wry[tid];
        strig[tid * 2 + 0] = __cosf(hy);
        strig[tid * 2 + 1] = __sinf(hy);
    }
    // ---- merged-RZ phase table: 256 entries (layers 0,1 x physical index p)
    if (tid < 2 * 128) {
        int l = tid >> 7, p = tid & 127;
        float th = (l == 0) ? rzph<0, 0>(wrz, p, 0.0f)
                            : rzph<1, 0>(wrz, p, 0.0f);
        sphz[tid * 2 + 0] = __cosf(th);
        sphz[tid * 2 + 1] = __sinf(th);
    }
    __syncthreads();

    int gtid = blockIdx.x * blockDim.x + tid;
    int wv   = gtid >> 6;
    int e0   = wv * 2;
    if (e0 >= B) {
        if (trdst) *trdst = f2bf(trv);
        return;
    }

    // data half-angle trig (hw sin/cos), elements packed in f32x2
    f32x2 dc[NQ], dsn[NQ];
#pragma unroll
    for (int i = 0; i < NQ; ++i) {
        float h0 = 0.5f * fmaf(scales[i], x_q[(size_t)e0 * NQ + i], biases[i]);
        float h1 = 0.5f * fmaf(scales[i], x_q[(size_t)(e0 + 1) * NQ + i], biases[i]);
        dc[i]  = (f32x2){__cosf(h0), __cosf(h1)};
        dsn[i] = (f32x2){__sinf(h0), __sinf(h1)};
    }

    // layer-0 combined (data+weight) RY block on |0...0>: product state (λ=id)
    f32x2 A0r, A0i = sp(0.0f), A1r, A1i = sp(0.0f);
    {
        f32x2 cl[NQ], sl[NQ];
#pragma unroll
        for (int i = 0; i < NQ; ++i) {
            float cw = strig[i * 2 + 0], sw = strig[i * 2 + 1];
            cl[i] = dc[i] * sp(cw) - dsn[i] * sp(sw);
            sl[i] = dsn[i] * sp(cw) + dc[i] * sp(sw);
        }
        f32x2 f1 = sel2(lane & 32, sl[1], cl[1]);
        f32x2 f2 = sel2(lane & 16, sl[2], cl[2]);
        f32x2 f3 = sel2(lane &  8, sl[3], cl[3]);
        f32x2 f4 = sel2(lane &  4, sl[4], cl[4]);
        f32x2 f5 = sel2(lane &  2, sl[5], cl[5]);
        f32x2 f6 = sel2(lane &  1, sl[6], cl[6]);
        f32x2 pr = (f1 * f2) * (f3 * f4) * (f5 * f6);
        A0r = pr * cl[0];
        A1r = pr * sl[0];
    }

    rztab<0>(sphz, lane, A0r, A0i, A1r, A1i);
    // CNOT block 1 deferred (λ -> LAM1)
    rygates<1, 0>(strig, dc, dsn, lane, A0r, A0i, A1r, A1i);
    rztab<1>(sphz, lane, A0r, A0i, A1r, A1i);
    // CNOT block 2 deferred (λ -> LAM2)
    rygates<2, 0>(strig, dc, dsn, lane, A0r, A0i, A1r, A1i);
    // layer-2 RZ: dead (phase-only, followed by permutation + |amp|^2) — skipped
    // CNOT block 3 deferred (λ -> LAM3, folded into feature masks)

    f32x2 p0 = A0r * A0r + A0i * A0i;
    f32x2 p1 = A1r * A1r + A1i * A1i;
    f32x2 tp = p0 + p1;   // physical-Walsh masks with bit6 = 0
    f32x2 tm = p0 - p1;   // physical-Walsh masks with bit6 = 1

    bfly2<1>(lane, tp, tm);
    bfly2<2>(lane, tp, tm);
    bfly2<4>(lane, tp, tm);
    bfly2<8>(lane, tp, tm);
    bfly2<16>(lane, tp, tm);
    bfly2<32>(lane, tp, tm);

    // ---- coalesced feature store: lane L<32 writes q_out[e0*16 + L]
    {
        constexpr unsigned P0 = pack_feat(0),  P1 = pack_feat(4);
        constexpr unsigned P2 = pack_feat(8),  P3 = pack_feat(12);
        int k = lane & 15;
        unsigned wlo  = (k & 4) ? P1 : P0;
        unsigned whi  = (k & 4) ? P3 : P2;
        unsigned word = (k & 8) ? whi : wlo;
        unsigned entry = (word >> ((k & 3) * 8)) & 127u;
        int addr   = (int)(entry & 63u) << 2;
        int useTm  = (int)(entry & 64u);
        int e      = (lane >> 4) & 1;
        float vpx = bpermf(addr, tp.x), vpy = bpermf(addr, tp.y);
        float vmx = bpermf(addr, tm.x), vmy = bpermf(addr, tm.y);
        float vp = e ? vpy : vpx;
        float vm = e ? vmy : vmx;
        float val = useTm ? vm : vp;
        if (lane < 32) q_out[(size_t)e0 * 16 + lane] = val;
    }

    // ---- epilogue: transpose store (load latency hidden by circuit above)
    if (trdst) *trdst = f2bf(trv);
}

// ---------------------------------------------------------------------------
// One MFMA layer (cooperative, 8 waves): Y[64][N] = act(X[64][K]@Wt^T + b).
//   8 waves split NTILES x 4 mtiles: each wave owns ONE ntile (= wv % NTILES)
//   and MT_W = NTILES/2 mtiles starting at (wv / NTILES) * MT_W.
// ---------------------------------------------------------------------------
template<int K, int NTILES, bool RELU>
__device__ __forceinline__ void layer_mfma8(
    const unsigned short* src, unsigned short* dst,
    const unsigned short* __restrict__ wt, const float* __restrict__ bias,
    int dstcol, int lane, int wv)
{
    constexpr int KB   = K / 32;
    constexpr int MT_W = (NTILES * 4) / 8;     // mtiles per wave
    const int ntile  = wv % NTILES;
    const int mtile0 = (wv / NTILES) * MT_W;
    const int lcol = lane & 15;
    const int lrow = lane >> 4;

    bf16x8 bfrag[KB];
    float  bb = bias[ntile * 16 + lcol];
#pragma unroll
    for (int kb = 0; kb < KB; ++kb)
        bfrag[kb] = *(const bf16x8*)&wt[(ntile * 16 + lcol) * K + kb * 32 + lrow * 8];

#pragma unroll
    for (int m = 0; m < MT_W; ++m) {
        const int mt = mtile0 + m;
        bf16x8 afrag[KB];
#pragma unroll
        for (int kb = 0; kb < KB; ++kb)
            afrag[kb] = *(const bf16x8*)&src[(mt * 16 + lcol) * LDS_S + kb * 32 + lrow * 8];

        f32x4 acc = (f32x4){bb, bb, bb, bb};
#pragma unroll
        for (int kb = 0; kb < KB; ++kb)
            acc = __builtin_amdgcn_mfma_f32_16x16x32_bf16(afrag[kb], bfrag[kb], acc, 0, 0, 0);

#pragma unroll
        for (int r = 0; r < 4; ++r) {
            float v = acc[r];
            if (RELU) v = fmaxf(v, 0.0f);
            dst[(mt * 16 + lrow * 4 + r) * LDS_S + dstcol + ntile * 16 + lcol] = f2bf(v);
        }
    }
}

// ---------------------------------------------------------------------------
// Fused MFMA MLP (cooperative, ROWS=64, 8 waves/block = 512 threads).
// ---------------------------------------------------------------------------
__global__ __launch_bounds__(512) void mlp_kernel(
    const float* __restrict__ q_out, const float* __restrict__ x_c,
    const unsigned short* __restrict__ ew1t, const float* __restrict__ eb1,
    const unsigned short* __restrict__ ew2t, const float* __restrict__ eb2,
    const unsigned short* __restrict__ w1t,  const float* __restrict__ b1,
    const unsigned short* __restrict__ w2t,  const float* __restrict__ b2,
    const unsigned short* __restrict__ w3t,  const float* __restrict__ b3,
    const unsigned short* __restrict__ w4t,  const float* __restrict__ b4,
    float* __restrict__ out, int B)
{
    __shared__ unsigned short BufA[ROWS * LDS_S];
    __shared__ unsigned short BufB[ROWS * LDS_S];

    const int tid  = threadIdx.x;
    const int lane = tid & 63;
    const int wv   = __builtin_amdgcn_readfirstlane(tid >> 6);   // 0..7
    const int base = blockIdx.x * ROWS;

    // ---- stage x_c (fp32 -> bf16) into BufA cols 0-63
    {
        const float4* xr = (const float4*)(x_c + (size_t)base * 64);
        for (int i = tid; i < 1024; i += 512) {
            int row = i >> 4, fc = i & 15;
            float4 v = xr[i];
            us4 b;
            b.x = f2bf(v.x); b.y = f2bf(v.y); b.z = f2bf(v.z); b.w = f2bf(v.w);
            *(us4*)&BufA[row * LDS_S + fc * 4] = b;
        }
    }
    // ---- stage q_out (stride 16) into BufA cols 64-79; junk cols 78-79 are
    //      overwritten by encL2 before fusion L1 reads them
    for (int i = tid; i < 1024; i += 512) {
        int row = i >> 4, k = i & 15;
        BufA[row * LDS_S + 64 + k] = f2bf(q_out[(size_t)(base + row) * 16 + k]);
    }
    // ---- zero pad cols 110-127
    for (int i = tid; i < 64 * 18; i += 512) {
        int row = i / 18, k = i - row * 18;
        BufA[row * LDS_S + 110 + k] = 0;
    }
    __syncthreads();

    layer_mfma8<64, 4, true>(BufA, BufB, ew1t, eb1, 0, lane, wv);
    __syncthreads();
    layer_mfma8<64, 2, true>(BufB, BufA, ew2t, eb2, 78, lane, wv);
    __syncthreads();
    layer_mfma8<128, 8, true>(BufA, BufB, w1t, b1, 0, lane, wv);
    __syncthreads();
    layer_mfma8<128, 4, true>(BufB, BufA, w2t, b2, 0, lane, wv);
    __syncthreads();
    layer_mfma8<64, 2, true>(BufA, BufB, w3t, b3, 0, lane, wv);
    __syncthreads();

    // ---- fusion L4: out = h3 @ w4 + b4   [K=32, N=1(pad 16)], waves 0-3
    if (wv < 4) {
        const int lcol = lane & 15;
        const int lrow = lane >> 4;
        bf16x8 a = *(const bf16x8*)&BufB[(wv * 16 + lcol) * LDS_S + lrow * 8];
        bf16x8 b = *(const bf16x8*)&w4t[lcol * 32 + lrow * 8];
        float bv = b4[0];
        f32x4 acc = (f32x4){bv, bv, bv, bv};
        acc = __builtin_amdgcn_mfma_f32_16x16x32_bf16(a, b, acc, 0, 0, 0);
        if (lcol == 0) {
            float4 o; o.x = acc[0]; o.y = acc[1]; o.z = acc[2]; o.w = acc[3];
            *(float4*)(out + base + wv * 16 + lrow * 4) = o;
        }
    }
}

// ---------------------------------------------------------------------------
extern "C" void kernel_launch(void* const* d_in, const int* in_sizes, int n_in,
                              void* d_out, int out_size, void* d_ws, size_t ws_size,
                              hipStream_t stream)
{
    const float* x_q     = (const float*)d_in[0];
    const float* x_c     = (const float*)d_in[1];
    const float* scales  = (const float*)d_in[2];
    const float* biases  = (const float*)d_in[3];
    const float* wry     = (const float*)d_in[4];
    const float* wrz     = (const float*)d_in[5];
    const float* enc_w1  = (const float*)d_in[6];
    const float* enc_b1  = (const float*)d_in[7];
    const float* enc_w2  = (const float*)d_in[8];
    const float* enc_b2  = (const float*)d_in[9];
    const float* fus_w1  = (const float*)d_in[10];
    const float* fus_b1  = (const float*)d_in[11];
    const float* fus_w2  = (const float*)d_in[12];
    const float* fus_b2  = (const float*)d_in[13];
    const float* fus_w3  = (const float*)d_in[14];
    const float* fus_b3  = (const float*)d_in[15];
    const float* fus_w4  = (const float*)d_in[16];
    const float* fus_b4  = (const float*)d_in[17];
    float* out = (float*)d_out;

    int B = in_sizes[0] / NQ;   // 32768

    float* ws    = (float*)d_ws;
    float* q_out = ws;                              // B*16 floats (padded)
    unsigned short* wsh = (unsigned short*)(q_out + (size_t)B * 16);
    unsigned short* w1t  = wsh;                     // 16384
    unsigned short* w2t  = w1t + 16384;             // 8192
    unsigned short* ew1t = w2t + 8192;              // 4096
    unsigned short* ew2t = ew1t + 4096;             // 2048
    unsigned short* w3t  = ew2t + 2048;             // 2048
    unsigned short* w4t  = w3t + 2048;              // 512

    int circ_blocks = ((B / 2) * 64 + 255) / 256;   // 2 elements per wave, 4096
    circuit_kernel<<<circ_blocks, 256, 0, stream>>>(
        x_q, scales, biases, wry, wrz,
        enc_w1, enc_w2, fus_w1, fus_w2, fus_w3, fus_w4,
        q_out, ew1t, ew2t, w1t, w2t, w3t, w4t, B);

    int row_blocks = B / ROWS;   // 512
    mlp_kernel<<<row_blocks, 512, 0, stream>>>(q_out, x_c,
                                               ew1t, enc_b1, ew2t, enc_b2,
                                               w1t, fus_b1, w2t, fus_b2,
                                               w3t, fus_b3, w4t, fus_b4,
                                               out, B);
}